// Round 4
// baseline (722.308 us; speedup 1.0000x reference)
//
#include <hip/hip_runtime.h>
#include <hip/hip_bf16.h>
#include <math.h>

typedef __bf16 bf16;
typedef __bf16 bf16x2 __attribute__((ext_vector_type(2)));
typedef __bf16 bf16x4 __attribute__((ext_vector_type(4)));
typedef __bf16 bf16x8 __attribute__((ext_vector_type(8)));
typedef float f32x4 __attribute__((ext_vector_type(4)));

#define D_MODEL 2048
#define SEQ 2048
#define BATCH 4
#define NH 16
#define DK 128

typedef const __attribute__((address_space(1))) void* as1_ptr;
typedef __attribute__((address_space(3))) void* as3_ptr;

__device__ __forceinline__ void gld_lds16(const bf16* g, bf16* l) {
  __builtin_amdgcn_global_load_lds((as1_ptr)g, (as3_ptr)l, 16, 0, 0);
}

// ---------------- fp32 -> bf16 conversion ----------------
__global__ void cvt_kernel(const float* __restrict__ in, bf16* __restrict__ out, int n8) {
  int i = blockIdx.x * 256 + threadIdx.x;
  if (i >= n8) return;
  long base = (long)i * 8;
  const float4* p = (const float4*)(in + base);
  float4 a = p[0], b = p[1];
  bf16x8 v;
  v[0] = (bf16)a.x; v[1] = (bf16)a.y; v[2] = (bf16)a.z; v[3] = (bf16)a.w;
  v[4] = (bf16)b.x; v[5] = (bf16)b.y; v[6] = (bf16)b.z; v[7] = (bf16)b.w;
  *(bf16x8*)(out + base) = v;
}

// 4 weight tensors in one dispatch (blockIdx.y selects)
__global__ void cvt4_kernel(const float* a, const float* b, const float* c, const float* d,
                            bf16* oa, bf16* ob, bf16* oc, bf16* od) {
  const float* in; bf16* out;
  switch (blockIdx.y) {
    case 0: in = a; out = oa; break;
    case 1: in = b; out = ob; break;
    case 2: in = c; out = oc; break;
    default: in = d; out = od; break;
  }
  int i = blockIdx.x * 256 + threadIdx.x;   // n8 = 524288, grid.x = 2048
  long base = (long)i * 8;
  const float4* p = (const float4*)(in + base);
  float4 x = p[0], y = p[1];
  bf16x8 v;
  v[0] = (bf16)x.x; v[1] = (bf16)x.y; v[2] = (bf16)x.z; v[3] = (bf16)x.w;
  v[4] = (bf16)y.x; v[5] = (bf16)y.y; v[6] = (bf16)y.z; v[7] = (bf16)y.w;
  *(bf16x8*)(out + base) = v;
}

// ---------------- GEMM: C[M,N] = A[M,K] * B[N,K]^T + bias ----------------
// m97 structure: 128x128 tile, BK=32, 4 waves (2x2), global_load_lds width 16.
// BIAS_ROW=0: bias indexed by column n; BIAS_ROW=1: bias indexed by row m.
template<int OUT_F32, int BIAS_ROW>
__global__ __launch_bounds__(256, 2)
void gemm_nt(const bf16* __restrict__ A, const bf16* __restrict__ B,
             const float* __restrict__ bias, void* __restrict__ Cout, int K, int ldc)
{
  __shared__ alignas(16) bf16 As[128 * 32];
  __shared__ alignas(16) bf16 Bs[128 * 32];
  const int tid  = threadIdx.x;
  const int wave = tid >> 6, lane = tid & 63;
  const int quad = lane >> 4, l16 = lane & 15;
  const int n0 = blockIdx.x * 128, m0 = blockIdx.y * 128;
  const int wm = (wave >> 1) * 64, wn = (wave & 1) * 64;

  const int srow = tid >> 2, scol = (tid & 3) * 8;
  const bf16* Ag1 = A + (long)(m0 + srow) * K + scol;
  const bf16* Ag2 = Ag1 + (long)64 * K;
  const bf16* Bg1 = B + (long)(n0 + srow) * K + scol;
  const bf16* Bg2 = Bg1 + (long)64 * K;
  bf16* Asw = As + wave * 512;
  bf16* Bsw = Bs + wave * 512;

  f32x4 acc[4][4] = {};
  for (int k0 = 0; k0 < K; k0 += 32) {
    __syncthreads();
    gld_lds16(Ag1 + k0, Asw);
    gld_lds16(Ag2 + k0, Asw + 2048);
    gld_lds16(Bg1 + k0, Bsw);
    gld_lds16(Bg2 + k0, Bsw + 2048);
    __syncthreads();
    bf16x8 Af[4], Bf[4];
    for (int mi = 0; mi < 4; mi++)
      Af[mi] = *(const bf16x8*)(&As[(wm + mi * 16 + l16) * 32 + quad * 8]);
    for (int ni = 0; ni < 4; ni++)
      Bf[ni] = *(const bf16x8*)(&Bs[(wn + ni * 16 + l16) * 32 + quad * 8]);
    for (int mi = 0; mi < 4; mi++)
      for (int ni = 0; ni < 4; ni++)
        acc[mi][ni] = __builtin_amdgcn_mfma_f32_16x16x32_bf16(Af[mi], Bf[ni], acc[mi][ni], 0, 0, 0);
  }

  float bv[4];
  if (!BIAS_ROW)
    for (int ni = 0; ni < 4; ni++) bv[ni] = bias[n0 + wn + ni * 16 + l16];
  for (int mi = 0; mi < 4; mi++)
    for (int r = 0; r < 4; r++) {
      long row = m0 + wm + mi * 16 + quad * 4 + r;
      float bm = BIAS_ROW ? bias[row] : 0.0f;
      for (int ni = 0; ni < 4; ni++) {
        float v = acc[mi][ni][r] + (BIAS_ROW ? bm : bv[ni]);
        long idx = row * (long)ldc + n0 + wn + ni * 16 + l16;
        if (OUT_F32) ((float*)Cout)[idx] = v;
        else         ((bf16*)Cout)[idx] = (bf16)v;
      }
    }
}

// ---------------- RoPE tables: ctab[pos][j] = {cos, sin}, j=0..63 ----------------
__global__ void ropetab_kernel(float* __restrict__ ctab) {
  int idx = blockIdx.x * 256 + threadIdx.x;   // 131072
  int j = idx & 63, p = idx >> 6;
  float f = exp2f(-(float)j * 0.20762050593046f);  // log2(10000)/64
  float th = (float)p * f;
  ctab[idx * 2]     = cosf(th);
  ctab[idx * 2 + 1] = sinf(th);
}

// ---------------- RoPE (NeoX rotate-half), in-place, table-driven ----------------
__global__ void rope_kernel(bf16* __restrict__ Q, bf16* __restrict__ K,
                            const float* __restrict__ ctab) {
  long idx = (long)blockIdx.x * 256 + threadIdx.x;   // 4194304 per tensor
  bf16* P = blockIdx.y ? K : Q;
  int i2 = (int)(idx & 31);          // dim pair (2*i2, 2*i2+1)
  int h  = (int)((idx >> 5) & 15);
  long row = idx >> 9;               // 0..8191
  int pos = (int)(row & (SEQ - 1));
  float4 cs = *(const float4*)(ctab + ((long)pos * 64 + 2 * i2) * 2); // c0,s0,c1,s1
  long base = row * D_MODEL + h * DK + 2 * i2;
  bf16x2 x1 = *(bf16x2*)(P + base);
  bf16x2 x2 = *(bf16x2*)(P + base + 64);
  bf16x2 y1, y2;
  y1[0] = (bf16)((float)x1[0] * cs.x - (float)x2[0] * cs.y);
  y2[0] = (bf16)((float)x2[0] * cs.x + (float)x1[0] * cs.y);
  y1[1] = (bf16)((float)x1[1] * cs.z - (float)x2[1] * cs.w);
  y2[1] = (bf16)((float)x2[1] * cs.z + (float)x1[1] * cs.w);
  *(bf16x2*)(P + base)      = y1;
  *(bf16x2*)(P + base + 64) = y2;
}

// ---------------- attention: O = softmax(Q K^T / sqrt(dk)) V ----------------
// S^T formulation, ni=4: each wave owns 64 q rows (QBLK=256/block, 4 waves,
// 256 thr). Round-3 post-mortem: wall = LDS+VALU+MFMA dependency mix; A-frag
// (Kf/Vf) LDS reads had only ni=2 reuse. ni=4 halves LDS reads per MFMA
// (25 -> 14.7 MB/CU). KVBLK=32 so LDS = K/V dbuf 32 KB + Ps 18 KB = 50 KB
// -> 2 blocks/CU. Grid 8x64=512 blocks = exactly 2/CU, zero tail.
// VGPR: Oacc 128 + Qf 64 + transients ~= 200 < 256 budget at (256,2).
__global__ __launch_bounds__(256, 2)
void attn_kernel(const bf16* __restrict__ Q, const bf16* __restrict__ K,
                 const bf16* __restrict__ Vt, bf16* __restrict__ O)
{
  __shared__ alignas(16) bf16 Ks[2][32 * 128];   // [s][d] swizzled, 2 x 8 KB
  __shared__ alignas(16) bf16 Vts[2][128 * 32];  // [d][s] swizzled, 2 x 8 KB
  __shared__ alignas(16) bf16 Ps[256 * 36];      // P^T [q][s=32 +pad4], wave-private rows (18 KB)
  const int tid  = threadIdx.x;
  const int wave = tid >> 6, lane = tid & 63;
  const int quad = lane >> 4, l16 = lane & 15;
  const int qt = blockIdx.x, bh = blockIdx.y;
  const int b = bh >> 4, h = bh & 15;
  const long qrow0 = (long)b * SEQ + qt * 256;
  const bf16* Qb = Q + qrow0 * D_MODEL + h * DK;
  const bf16* Kb = K + (long)b * SEQ * D_MODEL + h * DK;
  const bf16* Vb = Vt + (long)(h * DK) * (BATCH * SEQ) + b * SEQ;  // ld = 8192

  // Q as B-fragments, resident in registers all block (wave owns q rows wave*64..+63)
  bf16x8 Qf[4][4];
  for (int ni = 0; ni < 4; ni++)
    for (int ks = 0; ks < 4; ks++)
      Qf[ni][ks] = *(const bf16x8*)(Qb + (long)(wave * 64 + ni * 16 + l16) * D_MODEL + ks * 32 + quad * 8);

  // staging source pointers (swizzle on global side; LDS dest = base+lane*16)
  // K tile 32x128 = 8 KB = 8 groups of 1 KB; V^T tile 128x32 = 8 KB = 8 groups.
  // g = wave*2 + i. K group: 4 rows of 256 B; V group: 16 rows of 64 B.
  const bf16* Ksrc[2]; const bf16* Vsrc[2];
  for (int i = 0; i < 2; i++) {
    int g = wave * 2 + i;
    int rk = 4 * g + (lane >> 4);                 // K tile row 0..31
    int ck = l16 ^ (rk & 7);                      // global 16B-chunk for slot l16
    Ksrc[i] = Kb + (long)rk * D_MODEL + ck * 8;
    int rv = 16 * g + (lane >> 2);                // V tile row (d) 0..127
    int cv = (lane & 3) ^ ((rv >> 1) & 3);        // 4 chunks of 16 B per 64 B row
    Vsrc[i] = Vb + (long)rv * (BATCH * SEQ) + cv * 8;
  }

  f32x4 Oacc[8][4] = {};
  float lsum[4] = {0.0f, 0.0f, 0.0f, 0.0f};
  const float kSc = 0.088388347648318447f * 1.4426950408889634f; // (1/sqrt(128))*log2(e)
  const int swz = l16 & 7;
  const int vswz = (l16 >> 1) & 3;

  // prologue: stage tile 0 into buffer 0
  for (int i = 0; i < 2; i++) gld_lds16(Ksrc[i], &Ks[0][(wave * 2 + i) * 512]);
  for (int i = 0; i < 2; i++) gld_lds16(Vsrc[i], &Vts[0][(wave * 2 + i) * 512]);
  __syncthreads();

  int cur = 0;
  for (int kt = 32; kt <= SEQ; kt += 32) {
    // prefetch tile (kt) into the other buffer while computing tile (kt-32)
    if (kt < SEQ) {
      for (int i = 0; i < 2; i++)
        gld_lds16(Ksrc[i] + (long)kt * D_MODEL, &Ks[cur ^ 1][(wave * 2 + i) * 512]);
      for (int i = 0; i < 2; i++)
        gld_lds16(Vsrc[i] + kt, &Vts[cur ^ 1][(wave * 2 + i) * 512]);
    }
    const bf16* Ksb = Ks[cur];
    const bf16* Vsb = Vts[cur];

    // S^T = K · Q^T per 16-s group: A = K rows (s), B = Q rows (q)
    for (int si = 0; si < 2; si++) {
      bf16x8 Kf[4];
      for (int ks = 0; ks < 4; ks++) {
        int c = (ks * 4 + quad) ^ swz;            // row&7 == l16&7
        Kf[ks] = *(const bf16x8*)(&Ksb[(si * 16 + l16) * 128 + c * 8]);
      }
      f32x4 Sc[4] = {};
      __builtin_amdgcn_s_setprio(1);
      for (int ks = 0; ks < 4; ks++)
        for (int ni = 0; ni < 4; ni++)
          Sc[ni] = __builtin_amdgcn_mfma_f32_16x16x32_bf16(Kf[ks], Qf[ni][ks], Sc[ni], 0, 0, 0);
      __builtin_amdgcn_s_setprio(0);

      // P^T = exp(S^T * scale): pack 4 consecutive s per lane -> b64 stores
      for (int ni = 0; ni < 4; ni++) {
        bf16x4 pk;
        for (int r = 0; r < 4; r++) {
          float p = exp2f(Sc[ni][r] * kSc);
          lsum[ni] += p;
          pk[r] = (bf16)p;
        }
        *(bf16x4*)(&Ps[(wave * 64 + ni * 16 + l16) * 36 + si * 16 + quad * 4]) = pk;
      }
    }

    // O^T += Vt · P^T : A = Vt rows d, B = P^T rows q, K = 32 s-values
    bf16x8 Pf[4];
    for (int ni = 0; ni < 4; ni++)
      Pf[ni] = *(const bf16x8*)(&Ps[(wave * 64 + ni * 16 + l16) * 36 + quad * 8]);
    __builtin_amdgcn_s_setprio(1);
    for (int mi = 0; mi < 8; mi++) {
      int c = quad ^ vswz;
      bf16x8 Vf = *(const bf16x8*)(&Vsb[(mi * 16 + l16) * 32 + c * 8]);
      for (int ni = 0; ni < 4; ni++)
        Oacc[mi][ni] = __builtin_amdgcn_mfma_f32_16x16x32_bf16(Vf, Pf[ni], Oacc[mi][ni], 0, 0, 0);
    }
    __builtin_amdgcn_s_setprio(0);

    __syncthreads();   // drains vmcnt(0): tile (kt) loads were in flight all compute
    cur ^= 1;
  }

  // reduce row sums across the 4 quads (q lives on l16)
  for (int ni = 0; ni < 4; ni++) {
    lsum[ni] += __shfl_xor(lsum[ni], 16);
    lsum[ni] += __shfl_xor(lsum[ni], 32);
  }

  // epilogue: O^T C-layout -> O[q][d], 4 consecutive d per lane -> b64 stores
  for (int ni = 0; ni < 4; ni++) {
    float rinv = 1.0f / lsum[ni];
    long rowbase = (qrow0 + wave * 64 + ni * 16 + l16) * (long)D_MODEL + h * DK + quad * 4;
    for (int mi = 0; mi < 8; mi++) {
      bf16x4 o;
      for (int r = 0; r < 4; r++) o[r] = (bf16)(Oacc[mi][ni][r] * rinv);
      *(bf16x4*)(O + rowbase + mi * 16) = o;
    }
  }
}

// ---------------- host ----------------
extern "C" void kernel_launch(void* const* d_in, const int* in_sizes, int n_in,
                              void* d_out, int out_size, void* d_ws, size_t ws_size,
                              hipStream_t stream) {
  const float* x  = (const float*)d_in[0];
  const float* Wq = (const float*)d_in[1];
  const float* bq = (const float*)d_in[2];
  const float* Wk = (const float*)d_in[3];
  const float* bk = (const float*)d_in[4];
  const float* Wv = (const float*)d_in[5];
  const float* bv = (const float*)d_in[6];
  const float* Wo = (const float*)d_in[7];
  const float* bo = (const float*)d_in[8];
  float* out = (float*)d_out;

  bf16* ws = (bf16*)d_ws;
  // bf16 element offsets; total 160 MB.
  bf16* xb  = ws;                    // 16777216 elems (dead after VtF gemm)
  bf16* Wqb = ws + 16777216;         //  4194304 each
  bf16* Wkb = ws + 20971520;
  bf16* Wvb = ws + 25165824;
  bf16* Wob = ws + 29360128;
  bf16* Qp  = ws + 33554432;         // 16777216
  bf16* Kp  = ws + 50331648;
  bf16* VtF = ws + 67108864;         // V^T: [2048 d^][8192 b*s]
  float* ctab = (float*)ws;          // 1 MB, alive only between VtF gemm and attn
  bf16* O   = xb;                    // attention output overlays xb (and ctab) after rope

  cvt_kernel<<<8192, 256, 0, stream>>>(x, xb, 2097152);
  cvt4_kernel<<<dim3(2048, 4), 256, 0, stream>>>(Wq, Wk, Wv, Wo, Wqb, Wkb, Wvb, Wob);

  dim3 gg(16, 64);    // (N/128, M/128) for M=8192,N=2048
  gemm_nt<0, 0><<<gg, 256, 0, stream>>>(xb, Wqb, bq, Qp, 2048, 2048);
  gemm_nt<0, 0><<<gg, 256, 0, stream>>>(xb, Wkb, bk, Kp, 2048, 2048);
  // V^T = Wv · x^T : M=2048 (d^, row-bias bv), N=8192, ldc=8192
  gemm_nt<0, 1><<<dim3(64, 16), 256, 0, stream>>>(Wvb, xb, bv, VtF, 2048, 8192);

  ropetab_kernel<<<512, 256, 0, stream>>>(ctab);
  rope_kernel<<<dim3(16384, 2), 256, 0, stream>>>(Qp, Kp, ctab);

  attn_kernel<<<dim3(8, 64), 256, 0, stream>>>(Qp, Kp, VtF, O);

  gemm_nt<1, 0><<<gg, 256, 0, stream>>>(O, Wob, bo, out, 2048, 2048);
}

// Round 5
// 627.747 us; speedup vs baseline: 1.1506x; 1.1506x over previous
//
#include <hip/hip_runtime.h>
#include <hip/hip_bf16.h>
#include <math.h>

typedef __bf16 bf16;
typedef __bf16 bf16x2 __attribute__((ext_vector_type(2)));
typedef __bf16 bf16x4 __attribute__((ext_vector_type(4)));
typedef __bf16 bf16x8 __attribute__((ext_vector_type(8)));
typedef float f32x4 __attribute__((ext_vector_type(4)));

#define D_MODEL 2048
#define SEQ 2048
#define BATCH 4
#define NH 16
#define DK 128

typedef const __attribute__((address_space(1))) void* as1_ptr;
typedef __attribute__((address_space(3))) void* as3_ptr;

__device__ __forceinline__ void gld_lds16(const bf16* g, bf16* l) {
  __builtin_amdgcn_global_load_lds((as1_ptr)g, (as3_ptr)l, 16, 0, 0);
}

// ---------------- fp32 -> bf16 conversion ----------------
__global__ void cvt_kernel(const float* __restrict__ in, bf16* __restrict__ out, int n8) {
  int i = blockIdx.x * 256 + threadIdx.x;
  if (i >= n8) return;
  long base = (long)i * 8;
  const float4* p = (const float4*)(in + base);
  float4 a = p[0], b = p[1];
  bf16x8 v;
  v[0] = (bf16)a.x; v[1] = (bf16)a.y; v[2] = (bf16)a.z; v[3] = (bf16)a.w;
  v[4] = (bf16)b.x; v[5] = (bf16)b.y; v[6] = (bf16)b.z; v[7] = (bf16)b.w;
  *(bf16x8*)(out + base) = v;
}

// 4 weight tensors in one dispatch (blockIdx.y selects)
__global__ void cvt4_kernel(const float* a, const float* b, const float* c, const float* d,
                            bf16* oa, bf16* ob, bf16* oc, bf16* od) {
  const float* in; bf16* out;
  switch (blockIdx.y) {
    case 0: in = a; out = oa; break;
    case 1: in = b; out = ob; break;
    case 2: in = c; out = oc; break;
    default: in = d; out = od; break;
  }
  int i = blockIdx.x * 256 + threadIdx.x;   // n8 = 524288, grid.x = 2048
  long base = (long)i * 8;
  const float4* p = (const float4*)(in + base);
  float4 x = p[0], y = p[1];
  bf16x8 v;
  v[0] = (bf16)x.x; v[1] = (bf16)x.y; v[2] = (bf16)x.z; v[3] = (bf16)x.w;
  v[4] = (bf16)y.x; v[5] = (bf16)y.y; v[6] = (bf16)y.z; v[7] = (bf16)y.w;
  *(bf16x8*)(out + base) = v;
}

// ---------------- GEMM: C[M,N] = A[M,K] * B[N,K]^T + bias ----------------
// 256x256 tile, BK=64, 8 waves (2Mx4N), 512 threads, per m201 8-phase spirit:
// 2 full-tile LDS dbufs (128 KiB), raw s_barrier + counted vmcnt(8) so the
// distance-2 prefetch stays in flight ACROSS barriers (T3+T4), XOR chunk
// swizzle on LDS rows (T2: global-side pre-swizzle, involution on read),
// setprio around MFMA clusters (T5). Grid = (N/256, M/256) = 256 blocks
// = exactly 1 block/CU.
// Iter t (cur = t&1, tile T_t in buf[cur]):
//   vmcnt(8); barrier            <- T_t landed (T_{t+1}'s 8 loads may fly)
//   ds_read kstep0 frags; lgkmcnt(0); schedbar; setprio; 32 MFMA
//   ds_read kstep1 frags; lgkmcnt(0); schedbar; barrier
//   issue stage T_{t+2} -> buf[cur]   (8 gld_lds; tail iters re-stage last
//                                      tile into the dead buffer so vmcnt
//                                      bookkeeping stays uniform)
//   setprio; 32 MFMA
template<int OUT_F32, int BIAS_ROW>
__global__ __launch_bounds__(512, 2)
void gemm256(const bf16* __restrict__ A, const bf16* __restrict__ B,
             const float* __restrict__ bias, void* __restrict__ Cout, int K, int ldc)
{
  __shared__ alignas(16) bf16 As[2][256 * 64];
  __shared__ alignas(16) bf16 Bs[2][256 * 64];
  const int tid  = threadIdx.x;
  const int wave = tid >> 6, lane = tid & 63;
  const int quad = lane >> 4, l16 = lane & 15;
  const int n0 = blockIdx.x * 256, m0 = blockIdx.y * 256;
  const int wm = (wave >> 2) * 128, wn = (wave & 3) * 64;

  // staging: issue i (0..3) covers group g = wave*4+i (1 KB = 8 rows of 128 B).
  // LDS dest is linear (base + lane*16); the row-XOR chunk swizzle is applied
  // on the GLOBAL source address (m173 pattern): LDS[r][slot s] = A[r][s^(r&7)].
  const bf16* Asrc[4]; const bf16* Bsrc[4];
  for (int i = 0; i < 4; i++) {
    int g = wave * 4 + i;
    int r = g * 8 + (lane >> 3);                 // tile row 0..255
    int c = (lane & 7) ^ (r & 7);                // global 16B-chunk for slot lane&7
    Asrc[i] = A + (long)(m0 + r) * K + c * 8;
    Bsrc[i] = B + (long)(n0 + r) * K + c * 8;
  }

  f32x4 acc[8][4] = {};
  const int nt = K / 64;

  // prologue: stage T0 -> buf0, T1 -> buf1 (16 loads in flight)
  for (int i = 0; i < 4; i++) gld_lds16(Asrc[i],      &As[0][(wave * 4 + i) * 512]);
  for (int i = 0; i < 4; i++) gld_lds16(Bsrc[i],      &Bs[0][(wave * 4 + i) * 512]);
  for (int i = 0; i < 4; i++) gld_lds16(Asrc[i] + 64, &As[1][(wave * 4 + i) * 512]);
  for (int i = 0; i < 4; i++) gld_lds16(Bsrc[i] + 64, &Bs[1][(wave * 4 + i) * 512]);

  for (int t = 0; t < nt; t++) {
    const int cur = t & 1;
    asm volatile("s_waitcnt vmcnt(8)" ::: "memory");
    __builtin_amdgcn_s_barrier();
    const bf16* Ab = As[cur];
    const bf16* Bb = Bs[cur];

    // ---- kstep 0 ----
    bf16x8 Af[8], Bf[4];
    for (int mi = 0; mi < 8; mi++) {
      int ra = wm + mi * 16 + l16;
      int ch = quad ^ (ra & 7);
      Af[mi] = *(const bf16x8*)(&Ab[ra * 64 + ch * 8]);
    }
    for (int ni = 0; ni < 4; ni++) {
      int rb = wn + ni * 16 + l16;
      int ch = quad ^ (rb & 7);
      Bf[ni] = *(const bf16x8*)(&Bb[rb * 64 + ch * 8]);
    }
    asm volatile("s_waitcnt lgkmcnt(0)" ::: "memory");
    __builtin_amdgcn_sched_barrier(0);
    __builtin_amdgcn_s_setprio(1);
    for (int mi = 0; mi < 8; mi++)
      for (int ni = 0; ni < 4; ni++)
        acc[mi][ni] = __builtin_amdgcn_mfma_f32_16x16x32_bf16(Af[mi], Bf[ni], acc[mi][ni], 0, 0, 0);
    __builtin_amdgcn_s_setprio(0);

    // ---- kstep 1 ----
    for (int mi = 0; mi < 8; mi++) {
      int ra = wm + mi * 16 + l16;
      int ch = (4 + quad) ^ (ra & 7);
      Af[mi] = *(const bf16x8*)(&Ab[ra * 64 + ch * 8]);
    }
    for (int ni = 0; ni < 4; ni++) {
      int rb = wn + ni * 16 + l16;
      int ch = (4 + quad) ^ (rb & 7);
      Bf[ni] = *(const bf16x8*)(&Bb[rb * 64 + ch * 8]);
    }
    asm volatile("s_waitcnt lgkmcnt(0)" ::: "memory");
    __builtin_amdgcn_sched_barrier(0);
    __builtin_amdgcn_s_barrier();   // all waves done reading buf[cur]

    // stage T_{t+2} -> buf[cur] (overwrites; kstep1 frags already in regs)
    {
      long k0 = (long)((t + 2 < nt) ? (t + 2) : (nt - 1)) * 64;
      for (int i = 0; i < 4; i++) gld_lds16(Asrc[i] + k0, &As[cur][(wave * 4 + i) * 512]);
      for (int i = 0; i < 4; i++) gld_lds16(Bsrc[i] + k0, &Bs[cur][(wave * 4 + i) * 512]);
    }

    __builtin_amdgcn_s_setprio(1);
    for (int mi = 0; mi < 8; mi++)
      for (int ni = 0; ni < 4; ni++)
        acc[mi][ni] = __builtin_amdgcn_mfma_f32_16x16x32_bf16(Af[mi], Bf[ni], acc[mi][ni], 0, 0, 0);
    __builtin_amdgcn_s_setprio(0);
  }
  asm volatile("s_waitcnt vmcnt(0)" ::: "memory");   // drain dangling stages

  // epilogue (same layout conventions as verified 128^2 kernel)
  float bv[4];
  if (!BIAS_ROW)
    for (int ni = 0; ni < 4; ni++) bv[ni] = bias[n0 + wn + ni * 16 + l16];
  for (int mi = 0; mi < 8; mi++)
    for (int r = 0; r < 4; r++) {
      long row = m0 + wm + mi * 16 + quad * 4 + r;
      float bm = BIAS_ROW ? bias[row] : 0.0f;
      for (int ni = 0; ni < 4; ni++) {
        float v = acc[mi][ni][r] + (BIAS_ROW ? bm : bv[ni]);
        long idx = row * (long)ldc + n0 + wn + ni * 16 + l16;
        if (OUT_F32) ((float*)Cout)[idx] = v;
        else         ((bf16*)Cout)[idx] = (bf16)v;
      }
    }
}

// ---------------- RoPE tables: ctab[pos][j] = {cos, sin}, j=0..63 ----------------
__global__ void ropetab_kernel(float* __restrict__ ctab) {
  int idx = blockIdx.x * 256 + threadIdx.x;   // 131072
  int j = idx & 63, p = idx >> 6;
  float f = exp2f(-(float)j * 0.20762050593046f);  // log2(10000)/64
  float th = (float)p * f;
  ctab[idx * 2]     = cosf(th);
  ctab[idx * 2 + 1] = sinf(th);
}

// ---------------- RoPE (NeoX rotate-half), in-place, table-driven ----------------
__global__ void rope_kernel(bf16* __restrict__ Q, bf16* __restrict__ K,
                            const float* __restrict__ ctab) {
  long idx = (long)blockIdx.x * 256 + threadIdx.x;   // 4194304 per tensor
  bf16* P = blockIdx.y ? K : Q;
  int i2 = (int)(idx & 31);          // dim pair (2*i2, 2*i2+1)
  int h  = (int)((idx >> 5) & 15);
  long row = idx >> 9;               // 0..8191
  int pos = (int)(row & (SEQ - 1));
  float4 cs = *(const float4*)(ctab + ((long)pos * 64 + 2 * i2) * 2); // c0,s0,c1,s1
  long base = row * D_MODEL + h * DK + 2 * i2;
  bf16x2 x1 = *(bf16x2*)(P + base);
  bf16x2 x2 = *(bf16x2*)(P + base + 64);
  bf16x2 y1, y2;
  y1[0] = (bf16)((float)x1[0] * cs.x - (float)x2[0] * cs.y);
  y2[0] = (bf16)((float)x2[0] * cs.x + (float)x1[0] * cs.y);
  y1[1] = (bf16)((float)x1[1] * cs.z - (float)x2[1] * cs.w);
  y2[1] = (bf16)((float)x2[1] * cs.z + (float)x1[1] * cs.w);
  *(bf16x2*)(P + base)      = y1;
  *(bf16x2*)(P + base + 64) = y2;
}

// ---------------- attention: O = softmax(Q K^T / sqrt(dk)) V ----------------
// (identical to round-3: QBLK=128 / 4 waves / dbuf KVBLK=64 / s-halved Ps)
__global__ __launch_bounds__(256, 2)
void attn_kernel(const bf16* __restrict__ Q, const bf16* __restrict__ K,
                 const bf16* __restrict__ Vt, bf16* __restrict__ O)
{
  __shared__ alignas(16) bf16 Ks[2][64 * 128];   // [s][d] swizzled, 2 x 16 KB
  __shared__ alignas(16) bf16 Vts[2][128 * 64];  // [d][s] swizzled, 2 x 16 KB
  __shared__ alignas(16) bf16 Ps[128 * 36];      // half of P^T [q][s'=32 +pad4]
  const int tid  = threadIdx.x;
  const int wave = tid >> 6, lane = tid & 63;
  const int quad = lane >> 4, l16 = lane & 15;
  const int qt = blockIdx.x, bh = blockIdx.y;
  const int b = bh >> 4, h = bh & 15;
  const long qrow0 = (long)b * SEQ + qt * 128;
  const bf16* Qb = Q + qrow0 * D_MODEL + h * DK;
  const bf16* Kb = K + (long)b * SEQ * D_MODEL + h * DK;
  const bf16* Vb = Vt + (long)(h * DK) * (BATCH * SEQ) + b * SEQ;  // ld = 8192

  bf16x8 Qf[2][4];
  for (int ni = 0; ni < 2; ni++)
    for (int ks = 0; ks < 4; ks++)
      Qf[ni][ks] = *(const bf16x8*)(Qb + (long)(wave * 32 + ni * 16 + l16) * D_MODEL + ks * 32 + quad * 8);

  const bf16* Ksrc[4]; const bf16* Vsrc[4];
  for (int i = 0; i < 4; i++) {
    int g = wave * 4 + i;
    int rk = 4 * g + (lane >> 4);                 // K tile row 0..63
    int ck = l16 ^ (rk & 7);
    Ksrc[i] = Kb + (long)rk * D_MODEL + ck * 8;
    int rv = 8 * g + (lane >> 3);                 // V tile row 0..127
    int cv = (lane & 7) ^ (rv & 7);
    Vsrc[i] = Vb + (long)rv * (BATCH * SEQ) + cv * 8;
  }

  f32x4 Oacc[8][2] = {};
  float lsum[2] = {0.0f, 0.0f};
  const float kSc = 0.088388347648318447f * 1.4426950408889634f; // (1/sqrt(128))*log2(e)
  const int swz = l16 & 7;

  for (int i = 0; i < 4; i++) gld_lds16(Ksrc[i], &Ks[0][(wave * 4 + i) * 512]);
  for (int i = 0; i < 4; i++) gld_lds16(Vsrc[i], &Vts[0][(wave * 4 + i) * 512]);
  __syncthreads();

  int cur = 0;
  for (int kt = 64; kt <= SEQ; kt += 64) {
    if (kt < SEQ) {
      for (int i = 0; i < 4; i++)
        gld_lds16(Ksrc[i] + (long)kt * D_MODEL, &Ks[cur ^ 1][(wave * 4 + i) * 512]);
      for (int i = 0; i < 4; i++)
        gld_lds16(Vsrc[i] + kt, &Vts[cur ^ 1][(wave * 4 + i) * 512]);
    }
    const bf16* Ksb = Ks[cur];
    const bf16* Vsb = Vts[cur];

    for (int hh = 0; hh < 2; hh++) {
      f32x4 Sc[2][2] = {};
      __builtin_amdgcn_s_setprio(1);
      for (int ks = 0; ks < 4; ks++) {
        bf16x8 Kf[2];
        for (int j = 0; j < 2; j++) {
          int si = hh * 2 + j;
          int c = (ks * 4 + quad) ^ swz;
          Kf[j] = *(const bf16x8*)(&Ksb[(si * 16 + l16) * 128 + c * 8]);
        }
        for (int j = 0; j < 2; j++)
          for (int ni = 0; ni < 2; ni++)
            Sc[j][ni] = __builtin_amdgcn_mfma_f32_16x16x32_bf16(Kf[j], Qf[ni][ks], Sc[j][ni], 0, 0, 0);
      }
      __builtin_amdgcn_s_setprio(0);

      for (int j = 0; j < 2; j++)
        for (int ni = 0; ni < 2; ni++) {
          bf16x4 pk;
          for (int r = 0; r < 4; r++) {
            float p = exp2f(Sc[j][ni][r] * kSc);
            lsum[ni] += p;
            pk[r] = (bf16)p;
          }
          *(bf16x4*)(&Ps[(wave * 32 + ni * 16 + l16) * 36 + j * 16 + quad * 4]) = pk;
        }

      __builtin_amdgcn_s_setprio(1);
      bf16x8 Pf[2];
      for (int ni = 0; ni < 2; ni++)
        Pf[ni] = *(const bf16x8*)(&Ps[(wave * 32 + ni * 16 + l16) * 36 + quad * 8]);
      for (int mi = 0; mi < 8; mi++) {
        int c = (hh * 4 + quad) ^ swz;
        bf16x8 Vf = *(const bf16x8*)(&Vsb[(mi * 16 + l16) * 64 + c * 8]);
        for (int ni = 0; ni < 2; ni++)
          Oacc[mi][ni] = __builtin_amdgcn_mfma_f32_16x16x32_bf16(Vf, Pf[ni], Oacc[mi][ni], 0, 0, 0);
      }
      __builtin_amdgcn_s_setprio(0);
    }

    __syncthreads();
    cur ^= 1;
  }

  for (int ni = 0; ni < 2; ni++) {
    lsum[ni] += __shfl_xor(lsum[ni], 16);
    lsum[ni] += __shfl_xor(lsum[ni], 32);
  }

  for (int ni = 0; ni < 2; ni++) {
    float rinv = 1.0f / lsum[ni];
    long rowbase = (qrow0 + wave * 32 + ni * 16 + l16) * (long)D_MODEL + h * DK + quad * 4;
    for (int mi = 0; mi < 8; mi++) {
      bf16x4 o;
      for (int r = 0; r < 4; r++) o[r] = (bf16)(Oacc[mi][ni][r] * rinv);
      *(bf16x4*)(O + rowbase + mi * 16) = o;
    }
  }
}

// ---------------- host ----------------
extern "C" void kernel_launch(void* const* d_in, const int* in_sizes, int n_in,
                              void* d_out, int out_size, void* d_ws, size_t ws_size,
                              hipStream_t stream) {
  const float* x  = (const float*)d_in[0];
  const float* Wq = (const float*)d_in[1];
  const float* bq = (const float*)d_in[2];
  const float* Wk = (const float*)d_in[3];
  const float* bk = (const float*)d_in[4];
  const float* Wv = (const float*)d_in[5];
  const float* bv = (const float*)d_in[6];
  const float* Wo = (const float*)d_in[7];
  const float* bo = (const float*)d_in[8];
  float* out = (float*)d_out;

  bf16* ws = (bf16*)d_ws;
  // bf16 element offsets; total 160 MB.
  bf16* xb  = ws;                    // 16777216 elems (dead after VtF gemm)
  bf16* Wqb = ws + 16777216;         //  4194304 each
  bf16* Wkb = ws + 20971520;
  bf16* Wvb = ws + 25165824;
  bf16* Wob = ws + 29360128;
  bf16* Qp  = ws + 33554432;         // 16777216
  bf16* Kp  = ws + 50331648;
  bf16* VtF = ws + 67108864;         // V^T: [2048 d^][8192 b*s]
  float* ctab = (float*)ws;          // 1 MB, alive only between VtF gemm and attn
  bf16* O   = xb;                    // attention output overlays xb (and ctab) after rope

  cvt_kernel<<<8192, 256, 0, stream>>>(x, xb, 2097152);
  cvt4_kernel<<<dim3(2048, 4), 256, 0, stream>>>(Wq, Wk, Wv, Wo, Wqb, Wkb, Wvb, Wob);

  // 256^2 tiles: grid = (N/256, M/256)
  gemm256<0, 0><<<dim3(8, 32), 512, 0, stream>>>(xb, Wqb, bq, Qp, 2048, 2048);
  gemm256<0, 0><<<dim3(8, 32), 512, 0, stream>>>(xb, Wkb, bk, Kp, 2048, 2048);
  // V^T = Wv · x^T : M=2048 (d^, row-bias bv), N=8192, ldc=8192
  gemm256<0, 1><<<dim3(32, 8), 512, 0, stream>>>(Wvb, xb, bv, VtF, 2048, 8192);

  ropetab_kernel<<<512, 256, 0, stream>>>(ctab);
  rope_kernel<<<dim3(16384, 2), 256, 0, stream>>>(Qp, Kp, ctab);

  attn_kernel<<<dim3(16, 64), 256, 0, stream>>>(Qp, Kp, VtF, O);

  gemm256<1, 0><<<dim3(8, 32), 512, 0, stream>>>(O, Wob, bo, out, 2048, 2048);
}

// Round 8
// 626.129 us; speedup vs baseline: 1.1536x; 1.0026x over previous
//
#include <hip/hip_runtime.h>
#include <hip/hip_bf16.h>
#include <math.h>

typedef __bf16 bf16;
typedef __bf16 bf16x2 __attribute__((ext_vector_type(2)));
typedef __bf16 bf16x4 __attribute__((ext_vector_type(4)));
typedef __bf16 bf16x8 __attribute__((ext_vector_type(8)));
typedef float f32x4 __attribute__((ext_vector_type(4)));

#define D_MODEL 2048
#define SEQ 2048
#define BATCH 4
#define NH 16
#define DK 128

typedef const __attribute__((address_space(1))) void* as1_ptr;
typedef __attribute__((address_space(3))) void* as3_ptr;

__device__ __forceinline__ void gld_lds16(const bf16* g, bf16* l) {
  __builtin_amdgcn_global_load_lds((as1_ptr)g, (as3_ptr)l, 16, 0, 0);
}

// native 2^x: single v_exp_f32 via OCML's native variant (always linked by
// hipcc; it's the library exp2f itself routes through). Plain exp2f w/o
// fast-math expands to the denormal-safe __ocml_exp2_f32 sequence --
// measured as the dominant VALU cost in the attn softmax (R5: VALUBusy 47%,
// ~3.5x the hand count of the softmax path). Scores here are well-scaled;
// no denormal handling needed.
extern "C" __device__ float __ocml_native_exp2_f32(float);
__device__ __forceinline__ float fast_exp2(float x) {
  return __ocml_native_exp2_f32(x);
}

// ---------------- fp32 -> bf16 conversion ----------------
__global__ void cvt_kernel(const float* __restrict__ in, bf16* __restrict__ out, int n8) {
  int i = blockIdx.x * 256 + threadIdx.x;
  if (i >= n8) return;
  long base = (long)i * 8;
  const float4* p = (const float4*)(in + base);
  float4 a = p[0], b = p[1];
  bf16x8 v;
  v[0] = (bf16)a.x; v[1] = (bf16)a.y; v[2] = (bf16)a.z; v[3] = (bf16)a.w;
  v[4] = (bf16)b.x; v[5] = (bf16)b.y; v[6] = (bf16)b.z; v[7] = (bf16)b.w;
  *(bf16x8*)(out + base) = v;
}

// 4 weight tensors in one dispatch (blockIdx.y selects)
__global__ void cvt4_kernel(const float* a, const float* b, const float* c, const float* d,
                            bf16* oa, bf16* ob, bf16* oc, bf16* od) {
  const float* in; bf16* out;
  switch (blockIdx.y) {
    case 0: in = a; out = oa; break;
    case 1: in = b; out = ob; break;
    case 2: in = c; out = oc; break;
    default: in = d; out = od; break;
  }
  int i = blockIdx.x * 256 + threadIdx.x;   // n8 = 524288, grid.x = 2048
  long base = (long)i * 8;
  const float4* p = (const float4*)(in + base);
  float4 x = p[0], y = p[1];
  bf16x8 v;
  v[0] = (bf16)x.x; v[1] = (bf16)x.y; v[2] = (bf16)x.z; v[3] = (bf16)x.w;
  v[4] = (bf16)y.x; v[5] = (bf16)y.y; v[6] = (bf16)y.z; v[7] = (bf16)y.w;
  *(bf16x8*)(out + base) = v;
}

// ---------------- GEMM: C[M,N] = A[M,K] * B[N,K]^T + bias ----------------
// 256x256 tile, BK=64, 8 waves (2Mx4N), 512 threads, per m201 8-phase spirit:
// 2 full-tile LDS dbufs (128 KiB), raw s_barrier + counted vmcnt(8) so the
// distance-2 prefetch stays in flight ACROSS barriers (T3+T4), XOR chunk
// swizzle on LDS rows (T2: global-side pre-swizzle, involution on read),
// setprio around MFMA clusters (T5). Grid = (N/256, M/256) = 256 blocks
// = exactly 1 block/CU.  (R5: ~86 us each, ~800 TF, total -70 us vs 128^2.)
template<int OUT_F32, int BIAS_ROW>
__global__ __launch_bounds__(512, 2)
void gemm256(const bf16* __restrict__ A, const bf16* __restrict__ B,
             const float* __restrict__ bias, void* __restrict__ Cout, int K, int ldc)
{
  __shared__ alignas(16) bf16 As[2][256 * 64];
  __shared__ alignas(16) bf16 Bs[2][256 * 64];
  const int tid  = threadIdx.x;
  const int wave = tid >> 6, lane = tid & 63;
  const int quad = lane >> 4, l16 = lane & 15;
  const int n0 = blockIdx.x * 256, m0 = blockIdx.y * 256;
  const int wm = (wave >> 2) * 128, wn = (wave & 3) * 64;

  const bf16* Asrc[4]; const bf16* Bsrc[4];
  for (int i = 0; i < 4; i++) {
    int g = wave * 4 + i;
    int r = g * 8 + (lane >> 3);                 // tile row 0..255
    int c = (lane & 7) ^ (r & 7);                // global 16B-chunk for slot lane&7
    Asrc[i] = A + (long)(m0 + r) * K + c * 8;
    Bsrc[i] = B + (long)(n0 + r) * K + c * 8;
  }

  f32x4 acc[8][4] = {};
  const int nt = K / 64;

  // prologue: stage T0 -> buf0, T1 -> buf1 (16 loads in flight)
  for (int i = 0; i < 4; i++) gld_lds16(Asrc[i],      &As[0][(wave * 4 + i) * 512]);
  for (int i = 0; i < 4; i++) gld_lds16(Bsrc[i],      &Bs[0][(wave * 4 + i) * 512]);
  for (int i = 0; i < 4; i++) gld_lds16(Asrc[i] + 64, &As[1][(wave * 4 + i) * 512]);
  for (int i = 0; i < 4; i++) gld_lds16(Bsrc[i] + 64, &Bs[1][(wave * 4 + i) * 512]);

  for (int t = 0; t < nt; t++) {
    const int cur = t & 1;
    asm volatile("s_waitcnt vmcnt(8)" ::: "memory");
    __builtin_amdgcn_s_barrier();
    const bf16* Ab = As[cur];
    const bf16* Bb = Bs[cur];

    // ---- kstep 0 ----
    bf16x8 Af[8], Bf[4];
    for (int mi = 0; mi < 8; mi++) {
      int ra = wm + mi * 16 + l16;
      int ch = quad ^ (ra & 7);
      Af[mi] = *(const bf16x8*)(&Ab[ra * 64 + ch * 8]);
    }
    for (int ni = 0; ni < 4; ni++) {
      int rb = wn + ni * 16 + l16;
      int ch = quad ^ (rb & 7);
      Bf[ni] = *(const bf16x8*)(&Bb[rb * 64 + ch * 8]);
    }
    asm volatile("s_waitcnt lgkmcnt(0)" ::: "memory");
    __builtin_amdgcn_sched_barrier(0);
    __builtin_amdgcn_s_setprio(1);
    for (int mi = 0; mi < 8; mi++)
      for (int ni = 0; ni < 4; ni++)
        acc[mi][ni] = __builtin_amdgcn_mfma_f32_16x16x32_bf16(Af[mi], Bf[ni], acc[mi][ni], 0, 0, 0);
    __builtin_amdgcn_s_setprio(0);

    // ---- kstep 1 ----
    for (int mi = 0; mi < 8; mi++) {
      int ra = wm + mi * 16 + l16;
      int ch = (4 + quad) ^ (ra & 7);
      Af[mi] = *(const bf16x8*)(&Ab[ra * 64 + ch * 8]);
    }
    for (int ni = 0; ni < 4; ni++) {
      int rb = wn + ni * 16 + l16;
      int ch = (4 + quad) ^ (rb & 7);
      Bf[ni] = *(const bf16x8*)(&Bb[rb * 64 + ch * 8]);
    }
    asm volatile("s_waitcnt lgkmcnt(0)" ::: "memory");
    __builtin_amdgcn_sched_barrier(0);
    __builtin_amdgcn_s_barrier();   // all waves done reading buf[cur]

    // stage T_{t+2} -> buf[cur] (overwrites; kstep1 frags already in regs)
    {
      long k0 = (long)((t + 2 < nt) ? (t + 2) : (nt - 1)) * 64;
      for (int i = 0; i < 4; i++) gld_lds16(Asrc[i] + k0, &As[cur][(wave * 4 + i) * 512]);
      for (int i = 0; i < 4; i++) gld_lds16(Bsrc[i] + k0, &Bs[cur][(wave * 4 + i) * 512]);
    }

    __builtin_amdgcn_s_setprio(1);
    for (int mi = 0; mi < 8; mi++)
      for (int ni = 0; ni < 4; ni++)
        acc[mi][ni] = __builtin_amdgcn_mfma_f32_16x16x32_bf16(Af[mi], Bf[ni], acc[mi][ni], 0, 0, 0);
    __builtin_amdgcn_s_setprio(0);
  }
  asm volatile("s_waitcnt vmcnt(0)" ::: "memory");   // drain dangling stages

  // epilogue
  float bv[4];
  if (!BIAS_ROW)
    for (int ni = 0; ni < 4; ni++) bv[ni] = bias[n0 + wn + ni * 16 + l16];
  for (int mi = 0; mi < 8; mi++)
    for (int r = 0; r < 4; r++) {
      long row = m0 + wm + mi * 16 + quad * 4 + r;
      float bm = BIAS_ROW ? bias[row] : 0.0f;
      for (int ni = 0; ni < 4; ni++) {
        float v = acc[mi][ni][r] + (BIAS_ROW ? bm : bv[ni]);
        long idx = row * (long)ldc + n0 + wn + ni * 16 + l16;
        if (OUT_F32) ((float*)Cout)[idx] = v;
        else         ((bf16*)Cout)[idx] = (bf16)v;
      }
    }
}

// ---------------- RoPE tables: ctab[pos][j] = {cos, sin}, j=0..63 ----------------
__global__ void ropetab_kernel(float* __restrict__ ctab) {
  int idx = blockIdx.x * 256 + threadIdx.x;   // 131072
  int j = idx & 63, p = idx >> 6;
  float f = exp2f(-(float)j * 0.20762050593046f);  // log2(10000)/64
  float th = (float)p * f;
  ctab[idx * 2]     = cosf(th);
  ctab[idx * 2 + 1] = sinf(th);
}

// ---------------- RoPE (NeoX rotate-half), in-place, table-driven ----------------
__global__ void rope_kernel(bf16* __restrict__ Q, bf16* __restrict__ K,
                            const float* __restrict__ ctab) {
  long idx = (long)blockIdx.x * 256 + threadIdx.x;   // 4194304 per tensor
  bf16* P = blockIdx.y ? K : Q;
  int i2 = (int)(idx & 31);          // dim pair (2*i2, 2*i2+1)
  int h  = (int)((idx >> 5) & 15);
  long row = idx >> 9;               // 0..8191
  int pos = (int)(row & (SEQ - 1));
  float4 cs = *(const float4*)(ctab + ((long)pos * 64 + 2 * i2) * 2); // c0,s0,c1,s1
  long base = row * D_MODEL + h * DK + 2 * i2;
  bf16x2 x1 = *(bf16x2*)(P + base);
  bf16x2 x2 = *(bf16x2*)(P + base + 64);
  bf16x2 y1, y2;
  y1[0] = (bf16)((float)x1[0] * cs.x - (float)x2[0] * cs.y);
  y2[0] = (bf16)((float)x2[0] * cs.x + (float)x1[0] * cs.y);
  y1[1] = (bf16)((float)x1[1] * cs.z - (float)x2[1] * cs.w);
  y2[1] = (bf16)((float)x2[1] * cs.z + (float)x1[1] * cs.w);
  *(bf16x2*)(P + base)      = y1;
  *(bf16x2*)(P + base + 64) = y2;
}

// ---------------- attention: O = softmax(Q K^T / sqrt(dk)) V ----------------
// (structure identical to round-3/5; ONLY change vs R5: exp2f -> native
// v_exp_f32 via __ocml_native_exp2_f32. R5 post-mortem: VALUBusy 47% =
// ~1760 cyc/wave-iter, ~3.5x the hand count of the softmax path -- the gap
// matches __ocml_exp2_f32 libcall expansion.)
__global__ __launch_bounds__(256, 2)
void attn_kernel(const bf16* __restrict__ Q, const bf16* __restrict__ K,
                 const bf16* __restrict__ Vt, bf16* __restrict__ O)
{
  __shared__ alignas(16) bf16 Ks[2][64 * 128];   // [s][d] swizzled, 2 x 16 KB
  __shared__ alignas(16) bf16 Vts[2][128 * 64];  // [d][s] swizzled, 2 x 16 KB
  __shared__ alignas(16) bf16 Ps[128 * 36];      // half of P^T [q][s'=32 +pad4]
  const int tid  = threadIdx.x;
  const int wave = tid >> 6, lane = tid & 63;
  const int quad = lane >> 4, l16 = lane & 15;
  const int qt = blockIdx.x, bh = blockIdx.y;
  const int b = bh >> 4, h = bh & 15;
  const long qrow0 = (long)b * SEQ + qt * 128;
  const bf16* Qb = Q + qrow0 * D_MODEL + h * DK;
  const bf16* Kb = K + (long)b * SEQ * D_MODEL + h * DK;
  const bf16* Vb = Vt + (long)(h * DK) * (BATCH * SEQ) + b * SEQ;  // ld = 8192

  bf16x8 Qf[2][4];
  for (int ni = 0; ni < 2; ni++)
    for (int ks = 0; ks < 4; ks++)
      Qf[ni][ks] = *(const bf16x8*)(Qb + (long)(wave * 32 + ni * 16 + l16) * D_MODEL + ks * 32 + quad * 8);

  const bf16* Ksrc[4]; const bf16* Vsrc[4];
  for (int i = 0; i < 4; i++) {
    int g = wave * 4 + i;
    int rk = 4 * g + (lane >> 4);                 // K tile row 0..63
    int ck = l16 ^ (rk & 7);
    Ksrc[i] = Kb + (long)rk * D_MODEL + ck * 8;
    int rv = 8 * g + (lane >> 3);                 // V tile row 0..127
    int cv = (lane & 7) ^ (rv & 7);
    Vsrc[i] = Vb + (long)rv * (BATCH * SEQ) + cv * 8;
  }

  f32x4 Oacc[8][2] = {};
  float lsum[2] = {0.0f, 0.0f};
  const float kSc = 0.088388347648318447f * 1.4426950408889634f; // (1/sqrt(128))*log2(e)
  const int swz = l16 & 7;

  for (int i = 0; i < 4; i++) gld_lds16(Ksrc[i], &Ks[0][(wave * 4 + i) * 512]);
  for (int i = 0; i < 4; i++) gld_lds16(Vsrc[i], &Vts[0][(wave * 4 + i) * 512]);
  __syncthreads();

  int cur = 0;
  for (int kt = 64; kt <= SEQ; kt += 64) {
    if (kt < SEQ) {
      for (int i = 0; i < 4; i++)
        gld_lds16(Ksrc[i] + (long)kt * D_MODEL, &Ks[cur ^ 1][(wave * 4 + i) * 512]);
      for (int i = 0; i < 4; i++)
        gld_lds16(Vsrc[i] + kt, &Vts[cur ^ 1][(wave * 4 + i) * 512]);
    }
    const bf16* Ksb = Ks[cur];
    const bf16* Vsb = Vts[cur];

    for (int hh = 0; hh < 2; hh++) {
      f32x4 Sc[2][2] = {};
      __builtin_amdgcn_s_setprio(1);
      for (int ks = 0; ks < 4; ks++) {
        bf16x8 Kf[2];
        for (int j = 0; j < 2; j++) {
          int si = hh * 2 + j;
          int c = (ks * 4 + quad) ^ swz;
          Kf[j] = *(const bf16x8*)(&Ksb[(si * 16 + l16) * 128 + c * 8]);
        }
        for (int j = 0; j < 2; j++)
          for (int ni = 0; ni < 2; ni++)
            Sc[j][ni] = __builtin_amdgcn_mfma_f32_16x16x32_bf16(Kf[j], Qf[ni][ks], Sc[j][ni], 0, 0, 0);
      }
      __builtin_amdgcn_s_setprio(0);

      for (int j = 0; j < 2; j++)
        for (int ni = 0; ni < 2; ni++) {
          bf16x4 pk;
          for (int r = 0; r < 4; r++) {
            float p = fast_exp2(Sc[j][ni][r] * kSc);
            lsum[ni] += p;
            pk[r] = (bf16)p;
          }
          *(bf16x4*)(&Ps[(wave * 32 + ni * 16 + l16) * 36 + j * 16 + quad * 4]) = pk;
        }

      __builtin_amdgcn_s_setprio(1);
      bf16x8 Pf[2];
      for (int ni = 0; ni < 2; ni++)
        Pf[ni] = *(const bf16x8*)(&Ps[(wave * 32 + ni * 16 + l16) * 36 + quad * 8]);
      for (int mi = 0; mi < 8; mi++) {
        int c = (hh * 4 + quad) ^ swz;
        bf16x8 Vf = *(const bf16x8*)(&Vsb[(mi * 16 + l16) * 64 + c * 8]);
        for (int ni = 0; ni < 2; ni++)
          Oacc[mi][ni] = __builtin_amdgcn_mfma_f32_16x16x32_bf16(Vf, Pf[ni], Oacc[mi][ni], 0, 0, 0);
      }
      __builtin_amdgcn_s_setprio(0);
    }

    __syncthreads();
    cur ^= 1;
  }

  for (int ni = 0; ni < 2; ni++) {
    lsum[ni] += __shfl_xor(lsum[ni], 16);
    lsum[ni] += __shfl_xor(lsum[ni], 32);
  }

  for (int ni = 0; ni < 2; ni++) {
    float rinv = 1.0f / lsum[ni];
    long rowbase = (qrow0 + wave * 32 + ni * 16 + l16) * (long)D_MODEL + h * DK + quad * 4;
    for (int mi = 0; mi < 8; mi++) {
      bf16x4 o;
      for (int r = 0; r < 4; r++) o[r] = (bf16)(Oacc[mi][ni][r] * rinv);
      *(bf16x4*)(O + rowbase + mi * 16) = o;
    }
  }
}

// ---------------- host ----------------
extern "C" void kernel_launch(void* const* d_in, const int* in_sizes, int n_in,
                              void* d_out, int out_size, void* d_ws, size_t ws_size,
                              hipStream_t stream) {
  const float* x  = (const float*)d_in[0];
  const float* Wq = (const float*)d_in[1];
  const float* bq = (const float*)d_in[2];
  const float* Wk = (const float*)d_in[3];
  const float* bk = (const float*)d_in[4];
  const float* Wv = (const float*)d_in[5];
  const float* bv = (const float*)d_in[6];
  const float* Wo = (const float*)d_in[7];
  const float* bo = (const float*)d_in[8];
  float* out = (float*)d_out;

  bf16* ws = (bf16*)d_ws;
  // bf16 element offsets; total 160 MB.
  bf16* xb  = ws;                    // 16777216 elems (dead after VtF gemm)
  bf16* Wqb = ws + 16777216;         //  4194304 each
  bf16* Wkb = ws + 20971520;
  bf16* Wvb = ws + 25165824;
  bf16* Wob = ws + 29360128;
  bf16* Qp  = ws + 33554432;         // 16777216
  bf16* Kp  = ws + 50331648;
  bf16* VtF = ws + 67108864;         // V^T: [2048 d^][8192 b*s]
  float* ctab = (float*)ws;          // 1 MB, alive only between VtF gemm and attn
  bf16* O   = xb;                    // attention output overlays xb (and ctab) after rope

  cvt_kernel<<<8192, 256, 0, stream>>>(x, xb, 2097152);
  cvt4_kernel<<<dim3(2048, 4), 256, 0, stream>>>(Wq, Wk, Wv, Wo, Wqb, Wkb, Wvb, Wob);

  // 256^2 tiles: grid = (N/256, M/256)
  gemm256<0, 0><<<dim3(8, 32), 512, 0, stream>>>(xb, Wqb, bq, Qp, 2048, 2048);
  gemm256<0, 0><<<dim3(8, 32), 512, 0, stream>>>(xb, Wkb, bk, Kp, 2048, 2048);
  // V^T = Wv · x^T : M=2048 (d^, row-bias bv), N=8192, ldc=8192
  gemm256<0, 1><<<dim3(32, 8), 512, 0, stream>>>(Wvb, xb, bv, VtF, 2048, 8192);

  ropetab_kernel<<<512, 256, 0, stream>>>(ctab);
  rope_kernel<<<dim3(16384, 2), 256, 0, stream>>>(Qp, Kp, ctab);

  attn_kernel<<<dim3(16, 64), 256, 0, stream>>>(Qp, Kp, VtF, O);

  gemm256<1, 0><<<dim3(8, 32), 512, 0, stream>>>(O, Wob, bo, out, 2048, 2048);
}